// Round 3
// baseline (186.602 us; speedup 1.0000x reference)
//
#include <hip/hip_runtime.h>
#include <hip/hip_bf16.h>
#include <stdint.h>

// Problem constants (fixed by the reference)
#define B_DIM   128
#define N_DIM   36
#define C_DIM   1024
#define KNB     16
#define NKER    8
#define OUTD    1024
#define BN_NODES (B_DIM * N_DIM)     // 4608
#define E_EDGES  (BN_NODES * KNB)    // 73728
#define PI_F 3.14159265358979323846f

// GEMM tiling
#define TM  64
#define TN  128
#define BK  64
#define LDP 72          // padded LDS leading dim (bf16 units) — breaks bank conflicts
#define KITERS (C_DIM / BK)   // 16

typedef __attribute__((ext_vector_type(8))) short bf16x8;   // 8 bf16 = 4 VGPRs
typedef __attribute__((ext_vector_type(4))) float floatx4;  // MFMA C/D frag

struct alignas(8) U16x4 { unsigned short x, y, z, w; };

__device__ __forceinline__ unsigned short f2bf(float f) {
  union { float f; uint32_t u; } v; v.f = f;
  uint32_t u = v.u;
  return (unsigned short)((u + 0x7fffu + ((u >> 16) & 1u)) >> 16);  // RNE
}
__device__ __forceinline__ float bf2f(unsigned short h) {
  union { uint32_t u; float f; } v; v.u = ((uint32_t)h) << 16;
  return v.f;
}

// Raw barrier: waits only LDS ops (lgkmcnt), NOT vmcnt — in-flight global
// prefetch loads survive the barrier. "memory" clobber stops compiler
// reordering of LDS/global ops across it.
__device__ __forceinline__ void bar_sync() {
  asm volatile("s_waitcnt lgkmcnt(0)\n\ts_barrier" ::: "memory");
}

// ---------------------------------------------------------------------------
// Kernel 1: cast node_feats and conv_w (both fp32) to bf16
// ---------------------------------------------------------------------------
__global__ __launch_bounds__(256)
void cast_kernel(const float* __restrict__ feats,    // [BN*1024]
                 const float* __restrict__ cw,       // [1024*1024]
                 unsigned short* __restrict__ fb,
                 unsigned short* __restrict__ wb)
{
  const int NF4 = (BN_NODES * C_DIM) / 4;   // 1179648
  const int NW4 = (C_DIM * OUTD) / 4;       // 262144
  int tid = blockIdx.x * 256 + threadIdx.x;
  if (tid < NF4) {
    float4 v = ((const float4*)feats)[tid];
    U16x4 o = { f2bf(v.x), f2bf(v.y), f2bf(v.z), f2bf(v.w) };
    ((U16x4*)fb)[tid] = o;
  } else {
    int t = tid - NF4;
    if (t < NW4) {
      float4 v = ((const float4*)cw)[t];
      U16x4 o = { f2bf(v.x), f2bf(v.y), f2bf(v.z), f2bf(v.w) };
      ((U16x4*)wb)[t] = o;
    }
  }
}

// ---------------------------------------------------------------------------
// Kernel 2: proj = feats @ conv_w^T  [4608,1024] x [1024,1024]^T, bf16 MFMA.
// 64x128 tile (576 blocks, 2.25/CU), BK=64, 4 waves as 2x2 (32x64 each).
// Register-prefetch pipeline: global->VGPR (distance 2) -> ds_write (next
// iter) -> LDS dbuf -> frags -> MFMA. Compiler emits PRECISE per-register
// vmcnt before each ds_write; raw s_barrier carries no vmcnt drain, so
// prefetch loads stay in flight across iterations (the AITER pattern).
// ---------------------------------------------------------------------------
__global__ __launch_bounds__(256)
void gemm_bt(const unsigned short* __restrict__ A,    // [4608][1024] bf16
             const unsigned short* __restrict__ Bt,   // [1024][1024] bf16
             unsigned short* __restrict__ D)          // [4608][1024] bf16
{
  __shared__ unsigned short Alds[2 * TM * LDP];   // 2 x 9216 B
  __shared__ unsigned short Blds[2 * TN * LDP];   // 2 x 18432 B  (55 KB total)

  const int tid  = threadIdx.x;
  const int lane = tid & 63;
  const int wave = tid >> 6;
  const int wm   = wave >> 1;       // wave row (0..1) -> 32 rows each
  const int wn   = wave & 1;        // wave col (0..1) -> 64 cols each
  const int row0 = blockIdx.x * TM;
  const int col0 = blockIdx.y * TN;

  const int qk = (lane >> 4) << 3;  // k-offset within 32 (quad*8)
  const int lr = lane & 15;

  floatx4 acc[2][4] = {};

  // ---- staging maps: 16B chunks, chunk c -> row c>>3, kcol (c&7)*8 ----
  // A tile: 64x64 bf16 = 512 chunks -> thread t handles c = t, t+256
  // B tile: 128x64 bf16 = 1024 chunks -> c = t + 256*p, p=0..3
  const unsigned short* Ag = A  + (size_t)row0 * C_DIM;
  const unsigned short* Bg = Bt + (size_t)col0 * C_DIM;

  const int ac0 = tid, ac1 = tid + 256;
  const size_t aG0 = (size_t)(ac0 >> 3) * C_DIM + (ac0 & 7) * 8;
  const size_t aG1 = (size_t)(ac1 >> 3) * C_DIM + (ac1 & 7) * 8;
  const int    aL0 = (ac0 >> 3) * LDP + (ac0 & 7) * 8;
  const int    aL1 = (ac1 >> 3) * LDP + (ac1 & 7) * 8;

  size_t bG[4]; int bL[4];
#pragma unroll
  for (int p = 0; p < 4; ++p) {
    int c = tid + 256 * p;
    bG[p] = (size_t)(c >> 3) * C_DIM + (c & 7) * 8;
    bL[p] = (c >> 3) * LDP + (c & 7) * 8;
  }

  uint4 ra[2][2];   // [set][chunk]
  uint4 rb[2][4];

#define LOADT(S, KT) do {                                         \
    const unsigned short* ap = Ag + (size_t)(KT) * BK;            \
    const unsigned short* bp = Bg + (size_t)(KT) * BK;            \
    ra[S][0] = *(const uint4*)(ap + aG0);                         \
    ra[S][1] = *(const uint4*)(ap + aG1);                         \
    _Pragma("unroll") for (int p = 0; p < 4; ++p)                 \
      rb[S][p] = *(const uint4*)(bp + bG[p]);                     \
  } while (0)

#define STORET(S, BUF) do {                                       \
    *(uint4*)&Alds[(BUF) * TM * LDP + aL0] = ra[S][0];            \
    *(uint4*)&Alds[(BUF) * TM * LDP + aL1] = ra[S][1];            \
    _Pragma("unroll") for (int p = 0; p < 4; ++p)                 \
      *(uint4*)&Blds[(BUF) * TN * LDP + bL[p]] = rb[S][p];        \
  } while (0)

  // ---- prologue: tiles 0,1 into regs; tile 0 into LDS buf 0 ----
  LOADT(0, 0);
  LOADT(1, 1);
  STORET(0, 0);
  bar_sync();

  // ---- main loop, 2x-unrolled so stage indices are compile-time ----
  for (int it = 0; it < KITERS; it += 2) {
#pragma unroll
    for (int u = 0; u < 2; ++u) {
      const int i2 = it + u;        // current iteration index
      const int P  = u;             // buffer/set parity (it even)

      // fragment reads from LDS buf P (lgkm tracked; waited in bar_sync/MFMA)
      bf16x8 af[2][2], bb[4][2];
#pragma unroll
      for (int i = 0; i < 2; ++i)
#pragma unroll
        for (int h = 0; h < 2; ++h)
          af[i][h] = *(const bf16x8*)&Alds[P * TM * LDP +
                       (wm * 32 + i * 16 + lr) * LDP + h * 32 + qk];
#pragma unroll
      for (int j = 0; j < 4; ++j)
#pragma unroll
        for (int h = 0; h < 2; ++h)
          bb[j][h] = *(const bf16x8*)&Blds[P * TN * LDP +
                       (wn * 64 + j * 16 + lr) * LDP + h * 32 + qk];

      // prefetch tile i2+2 into the register set just freed (set P)
      if (i2 + 2 < KITERS) LOADT(P, i2 + 2);
      // hand off tile i2+1 (set 1-P) into the other LDS buffer;
      // compiler inserts precise vmcnt for set 1-P only
      if (i2 + 1 < KITERS) { STORET(1 - P, 1 - P); bar_sync(); }

#pragma unroll
      for (int i = 0; i < 2; ++i)
#pragma unroll
        for (int j = 0; j < 4; ++j)
#pragma unroll
          for (int h = 0; h < 2; ++h)
            acc[i][j] = __builtin_amdgcn_mfma_f32_16x16x32_bf16(
                af[i][h], bb[j][h], acc[i][j], 0, 0, 0);
    }
  }
#undef LOADT
#undef STORET

  // ---- epilogue: C/D layout col=lane&15, row=(lane>>4)*4+reg ----
  const int quad = lane >> 4;
#pragma unroll
  for (int i = 0; i < 2; ++i)
#pragma unroll
    for (int j = 0; j < 4; ++j)
#pragma unroll
      for (int r = 0; r < 4; ++r) {
        int row = row0 + wm * 32 + i * 16 + quad * 4 + r;
        int col = col0 + wn * 64 + j * 16 + lr;
        D[(size_t)row * OUTD + col] = f2bf(acc[i][j][r]);
      }
}

// ---------------------------------------------------------------------------
// Kernel 3: fused edge-weight + aggregate.
// Block n: compute 8x16 Gaussian-mixture weights for node n's edges, then
// out[n][c] = relu( sum_j ew[c/128][j] * proj[idx[n][j]][c] )
// ---------------------------------------------------------------------------
__global__ __launch_bounds__(256)
void agg_fused(const unsigned short* __restrict__ proj,  // [BN][1024] bf16
               const float* __restrict__ centre,         // [BN][2]
               const int*   __restrict__ nbr,            // [BN][16]
               const float* __restrict__ gw,             // [E]
               const float* __restrict__ mrho,
               const float* __restrict__ mth,
               const float* __restrict__ prho,
               const float* __restrict__ pth,
               float* __restrict__ out)                  // [BN][1024] fp32
{
  __shared__ int   idx[KNB];
  __shared__ float nx[KNB], ny[KNB];
  __shared__ float cc[2];
  __shared__ float wk[KNB][NKER];
  __shared__ float scl[KNB];
  __shared__ float ew[NKER][KNB];

  const int n = blockIdx.x;
  const int t = threadIdx.x;

  if (t < KNB) {
    int m = nbr[n * KNB + t];
    idx[t] = m;
    nx[t] = centre[2 * m];
    ny[t] = centre[2 * m + 1];
  } else if (t == KNB) {
    cc[0] = centre[2 * n];
    cc[1] = centre[2 * n + 1];
  }
  __syncthreads();

  if (t < 128) {                       // edge j = t>>3, kernel k = t&7
    int j = t >> 3, k = t & 7;
    float cx = cc[0] - nx[j];
    float cy = cc[1] - ny[j];
    float rho   = sqrtf(cx * cx + cy * cy);
    float theta = atan2f(cx, cy);      // jnp.arctan2(coord_x, coord_y)
    float dr = rho - mrho[k];
    float pr = prho[k];
    float w_r = expf(-0.5f * dr * dr / (1e-14f + pr * pr));
    float fa = fabsf(theta - mth[k]);
    float sa = fabsf(2.0f * PI_F - fa);
    float mm = fminf(fa, sa);
    float pt = pth[k];
    float w_t = expf(-0.5f * mm * mm / (1e-14f + pt * pt));
    float ww = w_r * w_t;
    wk[j][k] = (ww != ww) ? 0.f : ww;  // NaN guard (reference parity)
  }
  __syncthreads();

  if (t < KNB) {
    float s = 0.f;
#pragma unroll
    for (int k = 0; k < NKER; ++k) s += wk[t][k];
    scl[t] = gw[n * KNB + t] / s;
  }
  __syncthreads();

  if (t < 128) {
    int j = t >> 3, k = t & 7;
    ew[k][j] = wk[j][k] * scl[j];
  }
  __syncthreads();

  // main aggregate: thread t handles channels 4t..4t+3, k = t/32
  const int k = t >> 5;
  float a0 = 0.f, a1 = 0.f, a2 = 0.f, a3 = 0.f;
#pragma unroll
  for (int j = 0; j < KNB; ++j) {
    float wv = ew[k][j];               // LDS broadcast within 32-thread group
    U16x4 v = *(const U16x4*)&proj[(size_t)idx[j] * OUTD + t * 4];
    a0 += wv * bf2f(v.x);
    a1 += wv * bf2f(v.y);
    a2 += wv * bf2f(v.z);
    a3 += wv * bf2f(v.w);
  }
  float4 r;
  r.x = fmaxf(a0, 0.f); r.y = fmaxf(a1, 0.f);
  r.z = fmaxf(a2, 0.f); r.w = fmaxf(a3, 0.f);
  ((float4*)out)[(size_t)n * (OUTD / 4) + t] = r;
}

// ---------------------------------------------------------------------------
extern "C" void kernel_launch(void* const* d_in, const int* in_sizes, int n_in,
                              void* d_out, int out_size, void* d_ws, size_t ws_size,
                              hipStream_t stream)
{
  const float* feats  = (const float*)d_in[0];   // [128,36,1024]
  const float* centre = (const float*)d_in[1];   // [128,36,2]
  const int*   nbr    = (const int*)  d_in[2];   // [4608,16]
  const float* gw     = (const float*)d_in[3];   // [73728,1]
  const float* mrho   = (const float*)d_in[4];
  const float* mth    = (const float*)d_in[5];
  const float* prho   = (const float*)d_in[6];
  const float* pth    = (const float*)d_in[7];
  const float* cw     = (const float*)d_in[8];   // [8,128,1024] == [1024,1024]
  float* out = (float*)d_out;

  // workspace layout (total 20 MB)
  char* ws = (char*)d_ws;
  unsigned short* fb   = (unsigned short*)(ws);              //  9,437,184 B
  unsigned short* wb   = (unsigned short*)(ws + 9437184);    //  2,097,152 B
  unsigned short* proj = (unsigned short*)(ws + 11534336);   //  9,437,184 B

  cast_kernel<<<dim3(((BN_NODES * C_DIM) / 4 + (C_DIM * OUTD) / 4) / 256),
                dim3(256), 0, stream>>>(feats, cw, fb, wb);
  gemm_bt<<<dim3(BN_NODES / TM, OUTD / TN), dim3(256), 0, stream>>>(fb, wb, proj);
  agg_fused<<<dim3(BN_NODES), dim3(256), 0, stream>>>(
      proj, centre, nbr, gw, mrho, mth, prho, pth, out);
}

// Round 4
// 126.859 us; speedup vs baseline: 1.4709x; 1.4709x over previous
//
#include <hip/hip_runtime.h>
#include <hip/hip_bf16.h>
#include <stdint.h>

// Problem constants (fixed by the reference)
#define B_DIM   128
#define N_DIM   36
#define C_DIM   1024
#define KNB     16
#define NKER    8
#define OUTD    1024
#define BN_NODES (B_DIM * N_DIM)     // 4608
#define E_EDGES  (BN_NODES * KNB)    // 73728
#define PI_F 3.14159265358979323846f

// GEMM tiling: 128x128 tile, BK=128 (8 K-iters -> 8 barrier drains instead
// of 32; at 1.1 blocks/CU the drain is the serial cost, occupancy is moot)
#define TM 128
#define TN 128
#define BK 128
#define CLP 136        // epilogue C-tile LDS leading dim (16B-aligned rows)

typedef __attribute__((ext_vector_type(8))) short bf16x8;   // 8 bf16 = 4 VGPRs
typedef __attribute__((ext_vector_type(4))) float floatx4;  // MFMA C/D frag

struct alignas(8) U16x4 { unsigned short x, y, z, w; };

__device__ __forceinline__ unsigned short f2bf(float f) {
  union { float f; uint32_t u; } v; v.f = f;
  uint32_t u = v.u;
  return (unsigned short)((u + 0x7fffu + ((u >> 16) & 1u)) >> 16);  // RNE
}
__device__ __forceinline__ float bf2f(unsigned short h) {
  union { uint32_t u; float f; } v; v.u = ((uint32_t)h) << 16;
  return v.f;
}

// async global -> LDS, 16B per lane (global_load_lds_dwordx4).
// LDS side MUST be wave-uniform base + lane*16; global side may scatter.
__device__ __forceinline__ void gload16(const void* g, void* l) {
  __builtin_amdgcn_global_load_lds((__attribute__((address_space(1))) void*)(g),
                                   (__attribute__((address_space(3))) void*)(l),
                                   16, 0, 0);
}

// ---------------------------------------------------------------------------
// Kernel 1: cast node_feats and conv_w (both fp32) to bf16
// ---------------------------------------------------------------------------
__global__ __launch_bounds__(256)
void cast_kernel(const float* __restrict__ feats,    // [BN*1024]
                 const float* __restrict__ cw,       // [1024*1024]
                 unsigned short* __restrict__ fb,
                 unsigned short* __restrict__ wb)
{
  const int NF4 = (BN_NODES * C_DIM) / 4;   // 1179648
  const int NW4 = (C_DIM * OUTD) / 4;       // 262144
  int tid = blockIdx.x * 256 + threadIdx.x;
  if (tid < NF4) {
    float4 v = ((const float4*)feats)[tid];
    U16x4 o = { f2bf(v.x), f2bf(v.y), f2bf(v.z), f2bf(v.w) };
    ((U16x4*)fb)[tid] = o;
  } else {
    int t = tid - NF4;
    if (t < NW4) {
      float4 v = ((const float4*)cw)[t];
      U16x4 o = { f2bf(v.x), f2bf(v.y), f2bf(v.z), f2bf(v.w) };
      ((U16x4*)wb)[t] = o;
    }
  }
}

// ---------------------------------------------------------------------------
// Kernel 2: proj = feats @ conv_w^T  [4608,1024] x [1024,1024]^T, bf16 MFMA.
// m97 structure (global_load_lds + __syncthreads) with:
//  - BK=128: 8 iterations -> 8 vmcnt(0) barrier drains (was 32)
//  - XOR column swizzle on the GLOBAL side: LDS dst stays base+lane*16
//    (DMA constraint) while fragment ds_read_b128 becomes conflict-free
//  - LDS-staged epilogue: coalesced dwordx4 stores (kills the 11.6x
//    partial-sector write amplification seen in R3: WRITE 109MB for 9.4MB)
// ---------------------------------------------------------------------------
__global__ __launch_bounds__(256)
void gemm_bt(const unsigned short* __restrict__ A,    // [4608][1024] bf16
             const unsigned short* __restrict__ Bt,   // [1024][1024] bf16
             unsigned short* __restrict__ D)          // [4608][1024] bf16
{
  __shared__ unsigned short smem[TM * BK + TN * BK];  // 64 KB
  unsigned short* Al = smem;            // 128x128 bf16, 16B-chunk granular
  unsigned short* Bl = smem + TM * BK;

  const int tid  = threadIdx.x;
  const int lane = tid & 63;
  const int wave = tid >> 6;
  const int wr   = wave >> 1;       // wave row (0..1) -> 64 rows
  const int wc   = wave & 1;        // wave col (0..1) -> 64 cols
  const int row0 = blockIdx.x * TM;
  const int col0 = blockIdx.y * TN;

  const int q  = lane >> 4;         // quad
  const int lr = lane & 15;

  floatx4 acc[4][4] = {};

  // staging map: tile = 128 rows x 16 chunks (16B each) = 2048 chunks.
  // thread t handles chunks c = t + 256*i, i=0..7. LDS addr = c*16 (DMA
  // constraint satisfied). Global column is XOR-swizzled: chunk (row, qc)
  // in LDS holds global chunk (row, qc ^ (row&15)).
  int offA[8], offB[8];
#pragma unroll
  for (int i = 0; i < 8; ++i) {
    int c   = tid + 256 * i;
    int row = c >> 4, qc = c & 15;
    int sw  = qc ^ (row & 15);
    offA[i] = (row0 + row) * C_DIM + sw * 8;
    offB[i] = (col0 + row) * C_DIM + sw * 8;
  }

  for (int k0 = 0; k0 < C_DIM; k0 += BK) {
#pragma unroll
    for (int i = 0; i < 8; ++i) {
      gload16(A  + offA[i] + k0, &Al[(tid + 256 * i) * 8]);
      gload16(Bt + offB[i] + k0, &Bl[(tid + 256 * i) * 8]);
    }
    __syncthreads();   // compiler inserts vmcnt(0): DMA complete for all waves

#pragma unroll
    for (int kc = 0; kc < 4; ++kc) {
      // fragment (row r, k-chunk kc*4+q) lives at swizzled chunk
      // ((kc*4+q) ^ (r&15)); r&15 == lr for all i  ->  sc = (kc*4+q)^lr.
      const int sc = ((kc * 4 + q) ^ lr) * 8;
      bf16x8 af[4], bfr[4];
#pragma unroll
      for (int i = 0; i < 4; ++i) {
        af[i]  = *(const bf16x8*)&Al[(wr * 64 + i * 16 + lr) * BK + sc];
        bfr[i] = *(const bf16x8*)&Bl[(wc * 64 + i * 16 + lr) * BK + sc];
      }
#pragma unroll
      for (int i = 0; i < 4; ++i)
#pragma unroll
        for (int j = 0; j < 4; ++j)
          acc[i][j] = __builtin_amdgcn_mfma_f32_16x16x32_bf16(
              af[i], bfr[j], acc[i][j], 0, 0, 0);
    }
    __syncthreads();   // all waves done reading before next DMA overwrites
  }

  // ---- epilogue: stage C tile in LDS (bf16), then coalesced 16B stores ----
  unsigned short* Cl = smem;   // 128 x CLP ushorts = 34.8 KB, reuses Al/Bl
  // (last __syncthreads of the loop guarantees all frag reads are done)
#pragma unroll
  for (int i = 0; i < 4; ++i)
#pragma unroll
    for (int j = 0; j < 4; ++j)
#pragma unroll
      for (int r = 0; r < 4; ++r)
        Cl[(wr * 64 + i * 16 + q * 4 + r) * CLP + wc * 64 + j * 16 + lr] =
            f2bf(acc[i][j][r]);
  __syncthreads();
#pragma unroll
  for (int i = 0; i < 8; ++i) {
    int c = tid + 256 * i;
    int row = c >> 4, qc = c & 15;
    *(uint4*)&D[(size_t)(row0 + row) * OUTD + col0 + qc * 8] =
        *(const uint4*)&Cl[row * CLP + qc * 8];
  }
}

// ---------------------------------------------------------------------------
// Kernel 3: fused edge-weight + aggregate.
// Block n: compute 8x16 Gaussian-mixture weights for node n's edges, then
// out[n][c] = relu( sum_j ew[c/128][j] * proj[idx[n][j]][c] )
// ---------------------------------------------------------------------------
__global__ __launch_bounds__(256)
void agg_fused(const unsigned short* __restrict__ proj,  // [BN][1024] bf16
               const float* __restrict__ centre,         // [BN][2]
               const int*   __restrict__ nbr,            // [BN][16]
               const float* __restrict__ gw,             // [E]
               const float* __restrict__ mrho,
               const float* __restrict__ mth,
               const float* __restrict__ prho,
               const float* __restrict__ pth,
               float* __restrict__ out)                  // [BN][1024] fp32
{
  __shared__ int   idx[KNB];
  __shared__ float nx[KNB], ny[KNB];
  __shared__ float cc[2];
  __shared__ float wk[KNB][NKER];
  __shared__ float scl[KNB];
  __shared__ float ew[NKER][KNB];

  const int n = blockIdx.x;
  const int t = threadIdx.x;

  if (t < KNB) {
    int m = nbr[n * KNB + t];
    idx[t] = m;
    nx[t] = centre[2 * m];
    ny[t] = centre[2 * m + 1];
  } else if (t == KNB) {
    cc[0] = centre[2 * n];
    cc[1] = centre[2 * n + 1];
  }
  __syncthreads();

  if (t < 128) {                       // edge j = t>>3, kernel k = t&7
    int j = t >> 3, k = t & 7;
    float cx = cc[0] - nx[j];
    float cy = cc[1] - ny[j];
    float rho   = sqrtf(cx * cx + cy * cy);
    float theta = atan2f(cx, cy);      // jnp.arctan2(coord_x, coord_y)
    float dr = rho - mrho[k];
    float pr = prho[k];
    float w_r = expf(-0.5f * dr * dr / (1e-14f + pr * pr));
    float fa = fabsf(theta - mth[k]);
    float sa = fabsf(2.0f * PI_F - fa);
    float mm = fminf(fa, sa);
    float pt = pth[k];
    float w_t = expf(-0.5f * mm * mm / (1e-14f + pt * pt));
    float ww = w_r * w_t;
    wk[j][k] = (ww != ww) ? 0.f : ww;  // NaN guard (reference parity)
  }
  __syncthreads();

  if (t < KNB) {
    float s = 0.f;
#pragma unroll
    for (int k = 0; k < NKER; ++k) s += wk[t][k];
    scl[t] = gw[n * KNB + t] / s;
  }
  __syncthreads();

  if (t < 128) {
    int j = t >> 3, k = t & 7;
    ew[k][j] = wk[j][k] * scl[j];
  }
  __syncthreads();

  // main aggregate: thread t handles channels 4t..4t+3, k = t/32
  const int k = t >> 5;
  float a0 = 0.f, a1 = 0.f, a2 = 0.f, a3 = 0.f;
#pragma unroll
  for (int j = 0; j < KNB; ++j) {
    float wv = ew[k][j];               // LDS broadcast within 32-thread group
    U16x4 v = *(const U16x4*)&proj[(size_t)idx[j] * OUTD + t * 4];
    a0 += wv * bf2f(v.x);
    a1 += wv * bf2f(v.y);
    a2 += wv * bf2f(v.z);
    a3 += wv * bf2f(v.w);
  }
  float4 r;
  r.x = fmaxf(a0, 0.f); r.y = fmaxf(a1, 0.f);
  r.z = fmaxf(a2, 0.f); r.w = fmaxf(a3, 0.f);
  ((float4*)out)[(size_t)n * (OUTD / 4) + t] = r;
}

// ---------------------------------------------------------------------------
extern "C" void kernel_launch(void* const* d_in, const int* in_sizes, int n_in,
                              void* d_out, int out_size, void* d_ws, size_t ws_size,
                              hipStream_t stream)
{
  const float* feats  = (const float*)d_in[0];   // [128,36,1024]
  const float* centre = (const float*)d_in[1];   // [128,36,2]
  const int*   nbr    = (const int*)  d_in[2];   // [4608,16]
  const float* gw     = (const float*)d_in[3];   // [73728,1]
  const float* mrho   = (const float*)d_in[4];
  const float* mth    = (const float*)d_in[5];
  const float* prho   = (const float*)d_in[6];
  const float* pth    = (const float*)d_in[7];
  const float* cw     = (const float*)d_in[8];   // [8,128,1024] == [1024,1024]
  float* out = (float*)d_out;

  // workspace layout (total 20 MB)
  char* ws = (char*)d_ws;
  unsigned short* fb   = (unsigned short*)(ws);              //  9,437,184 B
  unsigned short* wb   = (unsigned short*)(ws + 9437184);    //  2,097,152 B
  unsigned short* proj = (unsigned short*)(ws + 11534336);   //  9,437,184 B

  cast_kernel<<<dim3(((BN_NODES * C_DIM) / 4 + (C_DIM * OUTD) / 4) / 256),
                dim3(256), 0, stream>>>(feats, cw, fb, wb);
  gemm_bt<<<dim3(BN_NODES / TM, OUTD / TN), dim3(256), 0, stream>>>(fb, wb, proj);
  agg_fused<<<dim3(BN_NODES), dim3(256), 0, stream>>>(
      proj, centre, nbr, gw, mrho, mth, prho, pth, out);
}

// Round 6
// 126.012 us; speedup vs baseline: 1.4808x; 1.0067x over previous
//
#include <hip/hip_runtime.h>
#include <hip/hip_bf16.h>
#include <stdint.h>

// Problem constants (fixed by the reference)
#define B_DIM   128
#define N_DIM   36
#define C_DIM   1024
#define KNB     16
#define NKER    8
#define OUTD    1024
#define BN_NODES (B_DIM * N_DIM)     // 4608
#define E_EDGES  (BN_NODES * KNB)    // 73728
#define PI_F 3.14159265358979323846f

// GEMM tiling: 128x128 tile, BK=64, double-buffered DMA (2 x 32 KB).
// One __syncthreads per iter; DMA for tile t+1 is issued AFTER the barrier,
// so the compiler's vmcnt(0)-before-barrier waits on a load that had a full
// compute phase to fly -> drain residue ~0.
#define TM 128
#define TN 128
#define BK 64
#define KIT (C_DIM / BK)   // 16
#define CLP 136            // epilogue C-tile LDS leading dim

typedef __attribute__((ext_vector_type(8))) short bf16x8;   // 8 bf16 = 4 VGPRs
typedef __attribute__((ext_vector_type(4))) float floatx4;  // MFMA C/D frag

struct alignas(8) U16x4 { unsigned short x, y, z, w; };

__device__ __forceinline__ unsigned short f2bf(float f) {
  union { float f; uint32_t u; } v; v.f = f;
  uint32_t u = v.u;
  return (unsigned short)((u + 0x7fffu + ((u >> 16) & 1u)) >> 16);  // RNE
}
__device__ __forceinline__ float bf2f(unsigned short h) {
  union { uint32_t u; float f; } v; v.u = ((uint32_t)h) << 16;
  return v.f;
}

// async global -> LDS, 16B per lane (global_load_lds_dwordx4).
// LDS side MUST be wave-uniform base + lane*16; global side may scatter.
__device__ __forceinline__ void gload16(const void* g, void* l) {
  __builtin_amdgcn_global_load_lds((__attribute__((address_space(1))) void*)(g),
                                   (__attribute__((address_space(3))) void*)(l),
                                   16, 0, 0);
}

// ---------------------------------------------------------------------------
// Kernel 1: cast node_feats and conv_w (both fp32) to bf16
// ---------------------------------------------------------------------------
__global__ __launch_bounds__(256)
void cast_kernel(const float* __restrict__ feats,    // [BN*1024]
                 const float* __restrict__ cw,       // [1024*1024]
                 unsigned short* __restrict__ fb,
                 unsigned short* __restrict__ wb)
{
  const int NF4 = (BN_NODES * C_DIM) / 4;   // 1179648
  const int NW4 = (C_DIM * OUTD) / 4;       // 262144
  int tid = blockIdx.x * 256 + threadIdx.x;
  if (tid < NF4) {
    float4 v = ((const float4*)feats)[tid];
    U16x4 o = { f2bf(v.x), f2bf(v.y), f2bf(v.z), f2bf(v.w) };
    ((U16x4*)fb)[tid] = o;
  } else {
    int t = tid - NF4;
    if (t < NW4) {
      float4 v = ((const float4*)cw)[t];
      U16x4 o = { f2bf(v.x), f2bf(v.y), f2bf(v.z), f2bf(v.w) };
      ((U16x4*)wb)[t] = o;
    }
  }
}

// ---------------------------------------------------------------------------
// Kernel 2: proj = feats @ conv_w^T  [4608,1024] x [1024,1024]^T, bf16 MFMA.
//  - double-buffered LDS (BK=64), ONE barrier per iter, DMA issued post-
//    barrier so it overlaps the whole compute phase of the same iteration
//  - XOR column swizzle on the GLOBAL side (conflict-free ds_read_b128,
//    LDS dst stays base+lane*16 as the DMA requires)
//  - LDS-staged epilogue: coalesced dwordx4 stores
// NOTE: no local pointer-to-LDS arrays (gfx950 rejects the addrspacecast
// static initializer) — buffer selection is by integer offset.
// ---------------------------------------------------------------------------
__global__ __launch_bounds__(256)
void gemm_bt(const unsigned short* __restrict__ A,    // [4608][1024] bf16
             const unsigned short* __restrict__ Bt,   // [1024][1024] bf16
             unsigned short* __restrict__ D)          // [4608][1024] bf16
{
  __shared__ unsigned short smem[4 * TM * BK];  // 64 KB: A0,A1,B0,B1 (8192 each)
  // layout: A buf p at offset p*TM*BK; B buf p at offset (2+p)*TM*BK

  const int tid  = threadIdx.x;
  const int lane = tid & 63;
  const int wave = tid >> 6;
  const int wr   = wave >> 1;       // wave row (0..1) -> 64 rows
  const int wc   = wave & 1;        // wave col (0..1) -> 64 cols
  const int row0 = blockIdx.x * TM;
  const int col0 = blockIdx.y * TN;

  const int q  = lane >> 4;         // quad
  const int lr = lane & 15;

  floatx4 acc[4][4] = {};

  // staging map: tile = 128 rows x 8 chunks (16B) = 1024 chunks; thread t
  // handles chunks c = t + 256*i, i=0..3. LDS addr = c*16 (DMA constraint).
  // Global column XOR-swizzled: LDS chunk (row,qc) holds global (row, qc^(row&7)).
  int offA[4], offB[4];
#pragma unroll
  for (int i = 0; i < 4; ++i) {
    int c   = tid + 256 * i;
    int row = c >> 3, qc = c & 7;
    int sw  = qc ^ (row & 7);
    offA[i] = (row0 + row) * C_DIM + sw * 8;
    offB[i] = (col0 + row) * C_DIM + sw * 8;
  }

#define DMA(T, P) do {                                                       \
    _Pragma("unroll") for (int i = 0; i < 4; ++i) {                          \
      gload16(A  + offA[i] + (T) * BK,                                       \
              &smem[(P) * TM * BK + (tid + 256 * i) * 8]);                   \
      gload16(Bt + offB[i] + (T) * BK,                                       \
              &smem[(2 + (P)) * TM * BK + (tid + 256 * i) * 8]);             \
    }                                                                        \
  } while (0)

  // prologue: tile 0 into buf 0
  DMA(0, 0);

  for (int t = 0; t < KIT; ++t) {
    const int p = t & 1;
    __syncthreads();                  // vmcnt(0): waits DMA(t) — overlapped
    if (t + 1 < KIT) DMA(t + 1, 1 - p);

    const int aBase = p * TM * BK;
    const int bBase = (2 + p) * TM * BK;
#pragma unroll
    for (int kc = 0; kc < 2; ++kc) {
      // frag (row r, chunk kc*4+q) stored at swizzled chunk ((kc*4+q)^(r&7));
      // r&7 == lr&7 for all frag rows  ->  sc = (kc*4+q) ^ (lr&7).
      const int sc = ((kc * 4 + q) ^ (lr & 7)) * 8;
      bf16x8 af[4], bfr[4];
#pragma unroll
      for (int i = 0; i < 4; ++i) {
        af[i]  = *(const bf16x8*)&smem[aBase + (wr * 64 + i * 16 + lr) * BK + sc];
        bfr[i] = *(const bf16x8*)&smem[bBase + (wc * 64 + i * 16 + lr) * BK + sc];
      }
#pragma unroll
      for (int i = 0; i < 4; ++i)
#pragma unroll
        for (int j = 0; j < 4; ++j)
          acc[i][j] = __builtin_amdgcn_mfma_f32_16x16x32_bf16(
              af[i], bfr[j], acc[i][j], 0, 0, 0);
    }
  }
#undef DMA

  // ---- epilogue: stage C tile in LDS (bf16), then coalesced 16B stores ----
  __syncthreads();                    // all frag reads done; reuse smem
#pragma unroll
  for (int i = 0; i < 4; ++i)
#pragma unroll
    for (int j = 0; j < 4; ++j)
#pragma unroll
      for (int r = 0; r < 4; ++r)
        smem[(wr * 64 + i * 16 + q * 4 + r) * CLP + wc * 64 + j * 16 + lr] =
            f2bf(acc[i][j][r]);
  __syncthreads();
#pragma unroll
  for (int i = 0; i < 8; ++i) {
    int c = tid + 256 * i;
    int row = c >> 4, qc = c & 15;
    *(uint4*)&D[(size_t)(row0 + row) * OUTD + col0 + qc * 8] =
        *(const uint4*)&smem[row * CLP + qc * 8];
  }
}

// ---------------------------------------------------------------------------
// Kernel 3: fused edge-weight + aggregate.
// Block n: compute 8x16 Gaussian-mixture weights for node n's edges, then
// out[n][c] = relu( sum_j ew[c/128][j] * proj[idx[n][j]][c] )
// ---------------------------------------------------------------------------
__global__ __launch_bounds__(256)
void agg_fused(const unsigned short* __restrict__ proj,  // [BN][1024] bf16
               const float* __restrict__ centre,         // [BN][2]
               const int*   __restrict__ nbr,            // [BN][16]
               const float* __restrict__ gw,             // [E]
               const float* __restrict__ mrho,
               const float* __restrict__ mth,
               const float* __restrict__ prho,
               const float* __restrict__ pth,
               float* __restrict__ out)                  // [BN][1024] fp32
{
  __shared__ int   idx[KNB];
  __shared__ float nx[KNB], ny[KNB];
  __shared__ float cc[2];
  __shared__ float wk[KNB][NKER];
  __shared__ float scl[KNB];
  __shared__ float ew[NKER][KNB];

  const int n = blockIdx.x;
  const int t = threadIdx.x;

  if (t < KNB) {
    int m = nbr[n * KNB + t];
    idx[t] = m;
    nx[t] = centre[2 * m];
    ny[t] = centre[2 * m + 1];
  } else if (t == KNB) {
    cc[0] = centre[2 * n];
    cc[1] = centre[2 * n + 1];
  }
  __syncthreads();

  if (t < 128) {                       // edge j = t>>3, kernel k = t&7
    int j = t >> 3, k = t & 7;
    float cx = cc[0] - nx[j];
    float cy = cc[1] - ny[j];
    float rho   = sqrtf(cx * cx + cy * cy);
    float theta = atan2f(cx, cy);      // jnp.arctan2(coord_x, coord_y)
    float dr = rho - mrho[k];
    float pr = prho[k];
    float w_r = expf(-0.5f * dr * dr / (1e-14f + pr * pr));
    float fa = fabsf(theta - mth[k]);
    float sa = fabsf(2.0f * PI_F - fa);
    float mm = fminf(fa, sa);
    float pt = pth[k];
    float w_t = expf(-0.5f * mm * mm / (1e-14f + pt * pt));
    float ww = w_r * w_t;
    wk[j][k] = (ww != ww) ? 0.f : ww;  // NaN guard (reference parity)
  }
  __syncthreads();

  if (t < KNB) {
    float s = 0.f;
#pragma unroll
    for (int k = 0; k < NKER; ++k) s += wk[t][k];
    scl[t] = gw[n * KNB + t] / s;
  }
  __syncthreads();

  if (t < 128) {
    int j = t >> 3, k = t & 7;
    ew[k][j] = wk[j][k] * scl[j];
  }
  __syncthreads();

  // main aggregate: thread t handles channels 4t..4t+3, k = t/32
  const int k = t >> 5;
  float a0 = 0.f, a1 = 0.f, a2 = 0.f, a3 = 0.f;
#pragma unroll
  for (int j = 0; j < KNB; ++j) {
    float wv = ew[k][j];               // LDS broadcast within 32-thread group
    U16x4 v = *(const U16x4*)&proj[(size_t)idx[j] * OUTD + t * 4];
    a0 += wv * bf2f(v.x);
    a1 += wv * bf2f(v.y);
    a2 += wv * bf2f(v.z);
    a3 += wv * bf2f(v.w);
  }
  float4 r;
  r.x = fmaxf(a0, 0.f); r.y = fmaxf(a1, 0.f);
  r.z = fmaxf(a2, 0.f); r.w = fmaxf(a3, 0.f);
  ((float4*)out)[(size_t)n * (OUTD / 4) + t] = r;
}

// ---------------------------------------------------------------------------
extern "C" void kernel_launch(void* const* d_in, const int* in_sizes, int n_in,
                              void* d_out, int out_size, void* d_ws, size_t ws_size,
                              hipStream_t stream)
{
  const float* feats  = (const float*)d_in[0];   // [128,36,1024]
  const float* centre = (const float*)d_in[1];   // [128,36,2]
  const int*   nbr    = (const int*)  d_in[2];   // [4608,16]
  const float* gw     = (const float*)d_in[3];   // [73728,1]
  const float* mrho   = (const float*)d_in[4];
  const float* mth    = (const float*)d_in[5];
  const float* prho   = (const float*)d_in[6];
  const float* pth    = (const float*)d_in[7];
  const float* cw     = (const float*)d_in[8];   // [8,128,1024] == [1024,1024]
  float* out = (float*)d_out;

  // workspace layout (total 20 MB)
  char* ws = (char*)d_ws;
  unsigned short* fb   = (unsigned short*)(ws);              //  9,437,184 B
  unsigned short* wb   = (unsigned short*)(ws + 9437184);    //  2,097,152 B
  unsigned short* proj = (unsigned short*)(ws + 11534336);   //  9,437,184 B

  cast_kernel<<<dim3(((BN_NODES * C_DIM) / 4 + (C_DIM * OUTD) / 4) / 256),
                dim3(256), 0, stream>>>(feats, cw, fb, wb);
  gemm_bt<<<dim3(BN_NODES / TM, OUTD / TN), dim3(256), 0, stream>>>(fb, wb, proj);
  agg_fused<<<dim3(BN_NODES), dim3(256), 0, stream>>>(
      proj, centre, nbr, gw, mrho, mth, prho, pth, out);
}

// Round 8
// 121.207 us; speedup vs baseline: 1.5395x; 1.0396x over previous
//
#include <hip/hip_runtime.h>
#include <hip/hip_bf16.h>
#include <stdint.h>

// Problem constants (fixed by the reference)
#define B_DIM   128
#define N_DIM   36
#define C_DIM   1024
#define KNB     16
#define NKER    8
#define OUTD    1024
#define BN_NODES (B_DIM * N_DIM)     // 4608
#define E_EDGES  (BN_NODES * KNB)    // 73728
#define PI_F 3.14159265358979323846f

// GEMM tiling: 64x128 tile (576 blocks -> 2.25/CU: fixes the 288-block
// 2x tail imbalance that held the 128x128 version at ~20 us), BK=64,
// double-buffered DMA, one barrier per iter.
#define TM 64
#define TN 128
#define BK 64
#define KIT (C_DIM / BK)   // 16
#define CLP 136            // epilogue C-tile LDS leading dim
// LDS shorts: A bufs 2*TM*BK = 8192, B bufs 2*TN*BK = 16384 -> 24576 (48 KB)
#define A_OFF(p) ((p) * TM * BK)            // 0 / 4096
#define B_OFF(p) (2 * TM * BK + (p) * TN * BK)  // 8192 / 16384

typedef __attribute__((ext_vector_type(8))) short bf16x8;   // 8 bf16 = 4 VGPRs
typedef __attribute__((ext_vector_type(4))) float floatx4;  // MFMA C/D frag

struct alignas(8) U16x4 { unsigned short x, y, z, w; };

__device__ __forceinline__ unsigned short f2bf(float f) {
  union { float f; uint32_t u; } v; v.f = f;
  uint32_t u = v.u;
  return (unsigned short)((u + 0x7fffu + ((u >> 16) & 1u)) >> 16);  // RNE
}
__device__ __forceinline__ float bf2f_lo(uint32_t pair) {
  union { uint32_t u; float f; } v; v.u = pair << 16;
  return v.f;
}
__device__ __forceinline__ float bf2f_hi(uint32_t pair) {
  union { uint32_t u; float f; } v; v.u = pair & 0xffff0000u;
  return v.f;
}

// async global -> LDS, 16B per lane (global_load_lds_dwordx4).
// LDS side MUST be wave-uniform base + lane*16; global side may scatter.
__device__ __forceinline__ void gload16(const void* g, void* l) {
  __builtin_amdgcn_global_load_lds((__attribute__((address_space(1))) void*)(g),
                                   (__attribute__((address_space(3))) void*)(l),
                                   16, 0, 0);
}

// ---------------------------------------------------------------------------
// Kernel 1: cast node_feats and conv_w (both fp32) to bf16
// ---------------------------------------------------------------------------
__global__ __launch_bounds__(256)
void cast_kernel(const float* __restrict__ feats,    // [BN*1024]
                 const float* __restrict__ cw,       // [1024*1024]
                 unsigned short* __restrict__ fb,
                 unsigned short* __restrict__ wb)
{
  const int NF4 = (BN_NODES * C_DIM) / 4;   // 1179648
  const int NW4 = (C_DIM * OUTD) / 4;       // 262144
  int tid = blockIdx.x * 256 + threadIdx.x;
  if (tid < NF4) {
    float4 v = ((const float4*)feats)[tid];
    U16x4 o = { f2bf(v.x), f2bf(v.y), f2bf(v.z), f2bf(v.w) };
    ((U16x4*)fb)[tid] = o;
  } else {
    int t = tid - NF4;
    if (t < NW4) {
      float4 v = ((const float4*)cw)[t];
      U16x4 o = { f2bf(v.x), f2bf(v.y), f2bf(v.z), f2bf(v.w) };
      ((U16x4*)wb)[t] = o;
    }
  }
}

// ---------------------------------------------------------------------------
// Kernel 2: proj = feats @ conv_w^T  [4608,1024] x [1024,1024]^T, bf16 MFMA.
// 64x128 tile, 4 waves as 2x2 (32x64 each), dbuf BK=64, XOR swizzle,
// LDS-staged coalesced epilogue.
// R8 FIX: epilogue store loop now covers the full 64x128 C tile
// (1024 chunks: i<4, row=c>>4, qc=c&15). R7 used the A-staging geometry
// (512 chunks, 8 chunks/row) and left cols 64..127 of proj as poison.
// ---------------------------------------------------------------------------
__global__ __launch_bounds__(256)
void gemm_bt(const unsigned short* __restrict__ A,    // [4608][1024] bf16
             const unsigned short* __restrict__ Bt,   // [1024][1024] bf16
             unsigned short* __restrict__ D)          // [4608][1024] bf16
{
  __shared__ unsigned short smem[2 * TM * BK + 2 * TN * BK];  // 48 KB

  const int tid  = threadIdx.x;
  const int lane = tid & 63;
  const int wave = tid >> 6;
  const int wm   = wave >> 1;       // wave row (0..1) -> 32 rows each
  const int wn   = wave & 1;        // wave col (0..1) -> 64 cols each
  const int row0 = blockIdx.x * TM;
  const int col0 = blockIdx.y * TN;

  const int q  = lane >> 4;         // quad
  const int lr = lane & 15;

  floatx4 acc[2][4] = {};

  // staging maps (16B chunks, chunk c -> row c>>3, qcol c&7, XOR swizzle):
  // A tile 64x8 chunks = 512 -> thread t does c = t + 256*i, i<2
  // B tile 128x8 chunks = 1024 -> c = t + 256*i, i<4
  int offA[2], offB[4];
#pragma unroll
  for (int i = 0; i < 2; ++i) {
    int c = tid + 256 * i, row = c >> 3, qc = c & 7;
    offA[i] = (row0 + row) * C_DIM + (qc ^ (row & 7)) * 8;
  }
#pragma unroll
  for (int i = 0; i < 4; ++i) {
    int c = tid + 256 * i, row = c >> 3, qc = c & 7;
    offB[i] = (col0 + row) * C_DIM + (qc ^ (row & 7)) * 8;
  }

#define DMA(T, P) do {                                                       \
    _Pragma("unroll") for (int i = 0; i < 2; ++i)                            \
      gload16(A + offA[i] + (T) * BK,                                        \
              &smem[A_OFF(P) + (tid + 256 * i) * 8]);                        \
    _Pragma("unroll") for (int i = 0; i < 4; ++i)                            \
      gload16(Bt + offB[i] + (T) * BK,                                       \
              &smem[B_OFF(P) + (tid + 256 * i) * 8]);                        \
  } while (0)

  DMA(0, 0);   // prologue: tile 0 into buf 0

  for (int t = 0; t < KIT; ++t) {
    const int p = t & 1;
    __syncthreads();                  // vmcnt(0): waits DMA(t) — overlapped
    if (t + 1 < KIT) DMA(t + 1, 1 - p);

    const int aBase = A_OFF(p);
    const int bBase = B_OFF(p);
#pragma unroll
    for (int kc = 0; kc < 2; ++kc) {
      // frag (row r, chunk kc*4+q) at swizzled chunk ((kc*4+q)^(r&7));
      // r mod 8 == lr mod 8 for all frag rows -> sc = (kc*4+q)^(lr&7).
      const int sc = ((kc * 4 + q) ^ (lr & 7)) * 8;
      bf16x8 af[2], bfr[4];
#pragma unroll
      for (int i = 0; i < 2; ++i)
        af[i]  = *(const bf16x8*)&smem[aBase + (wm * 32 + i * 16 + lr) * BK + sc];
#pragma unroll
      for (int j = 0; j < 4; ++j)
        bfr[j] = *(const bf16x8*)&smem[bBase + (wn * 64 + j * 16 + lr) * BK + sc];
#pragma unroll
      for (int i = 0; i < 2; ++i)
#pragma unroll
        for (int j = 0; j < 4; ++j)
          acc[i][j] = __builtin_amdgcn_mfma_f32_16x16x32_bf16(
              af[i], bfr[j], acc[i][j], 0, 0, 0);
    }
  }
#undef DMA

  // ---- epilogue: stage C tile (64x128 bf16) in LDS, coalesced stores ----
  __syncthreads();
#pragma unroll
  for (int i = 0; i < 2; ++i)
#pragma unroll
    for (int j = 0; j < 4; ++j)
#pragma unroll
      for (int r = 0; r < 4; ++r)
        smem[(wm * 32 + i * 16 + q * 4 + r) * CLP + wn * 64 + j * 16 + lr] =
            f2bf(acc[i][j][r]);
  __syncthreads();
  // full tile = 64 rows x 16 chunks = 1024 chunks; thread t does 4
#pragma unroll
  for (int i = 0; i < 4; ++i) {
    int c = tid + 256 * i;
    int row = c >> 4, qc = c & 15;
    *(uint4*)&D[(size_t)(row0 + row) * OUTD + col0 + qc * 8] =
        *(const uint4*)&smem[row * CLP + qc * 8];
  }
}

// ---------------------------------------------------------------------------
// Kernel 3: fused edge-weight + aggregate, 2 nodes per block.
// Threads 0-127 -> node 2b, 128-255 -> node 2b+1; thread u (=t&127) owns
// channels 8u..8u+7 (one uint4 gather per neighbor).
// ---------------------------------------------------------------------------
__global__ __launch_bounds__(256)
void agg_fused(const unsigned short* __restrict__ proj,  // [BN][1024] bf16
               const float* __restrict__ centre,         // [BN][2]
               const int*   __restrict__ nbr,            // [BN][16]
               const float* __restrict__ gw,             // [E]
               const float* __restrict__ mrho,
               const float* __restrict__ mth,
               const float* __restrict__ prho,
               const float* __restrict__ pth,
               float* __restrict__ out)                  // [BN][1024] fp32
{
  __shared__ int   idx[2][KNB];
  __shared__ float nxy[2][KNB][2];
  __shared__ float cxy[2][2];
  __shared__ float wk[2][KNB][NKER];
  __shared__ float scl[2][KNB];
  __shared__ float ew[2][NKER][KNB];

  const int n0   = blockIdx.x * 2;
  const int t    = threadIdx.x;
  const int half = t >> 7;
  const int u    = t & 127;

  if (t < 32) {
    int h = t >> 4, j = t & 15;
    int m = nbr[(n0 + h) * KNB + j];
    idx[h][j] = m;
    nxy[h][j][0] = centre[2 * m];
    nxy[h][j][1] = centre[2 * m + 1];
  } else if (t < 34) {
    int h = t - 32;
    cxy[h][0] = centre[2 * (n0 + h)];
    cxy[h][1] = centre[2 * (n0 + h) + 1];
  }
  __syncthreads();

  {                                    // 256 threads = 2 nodes x 16 edges x 8 k
    int j = u >> 3, k = u & 7;
    float cx = cxy[half][0] - nxy[half][j][0];
    float cy = cxy[half][1] - nxy[half][j][1];
    float rho   = sqrtf(cx * cx + cy * cy);
    float theta = atan2f(cx, cy);      // jnp.arctan2(coord_x, coord_y)
    float dr = rho - mrho[k];
    float pr = prho[k];
    float w_r = expf(-0.5f * dr * dr / (1e-14f + pr * pr));
    float fa = fabsf(theta - mth[k]);
    float sa = fabsf(2.0f * PI_F - fa);
    float mm = fminf(fa, sa);
    float pt = pth[k];
    float w_t = expf(-0.5f * mm * mm / (1e-14f + pt * pt));
    float ww = w_r * w_t;
    wk[half][j][k] = (ww != ww) ? 0.f : ww;   // NaN guard (reference parity)
  }
  __syncthreads();

  if (u < KNB) {
    float s = 0.f;
#pragma unroll
    for (int k = 0; k < NKER; ++k) s += wk[half][u][k];
    scl[half][u] = gw[(n0 + half) * KNB + u] / s;
  }
  __syncthreads();

  {
    int j = u >> 3, k = u & 7;
    ew[half][k][j] = wk[half][j][k] * scl[half][j];
  }
  __syncthreads();

  // main aggregate: thread u -> channels 8u..8u+7 (kernel block k = u/16)
  const int n = n0 + half;
  const int k = u >> 4;
  float a[8] = {0.f, 0.f, 0.f, 0.f, 0.f, 0.f, 0.f, 0.f};
#pragma unroll
  for (int j = 0; j < KNB; ++j) {
    float wv = ew[half][k][j];
    uint4 v = *(const uint4*)&proj[(size_t)idx[half][j] * OUTD + u * 8];
    a[0] += wv * bf2f_lo(v.x);  a[1] += wv * bf2f_hi(v.x);
    a[2] += wv * bf2f_lo(v.y);  a[3] += wv * bf2f_hi(v.y);
    a[4] += wv * bf2f_lo(v.z);  a[5] += wv * bf2f_hi(v.z);
    a[6] += wv * bf2f_lo(v.w);  a[7] += wv * bf2f_hi(v.w);
  }
  float4 r0, r1;
  r0.x = fmaxf(a[0], 0.f); r0.y = fmaxf(a[1], 0.f);
  r0.z = fmaxf(a[2], 0.f); r0.w = fmaxf(a[3], 0.f);
  r1.x = fmaxf(a[4], 0.f); r1.y = fmaxf(a[5], 0.f);
  r1.z = fmaxf(a[6], 0.f); r1.w = fmaxf(a[7], 0.f);
  float* o = out + (size_t)n * OUTD + u * 8;
  *(float4*)(o)     = r0;
  *(float4*)(o + 4) = r1;
}

// ---------------------------------------------------------------------------
extern "C" void kernel_launch(void* const* d_in, const int* in_sizes, int n_in,
                              void* d_out, int out_size, void* d_ws, size_t ws_size,
                              hipStream_t stream)
{
  const float* feats  = (const float*)d_in[0];   // [128,36,1024]
  const float* centre = (const float*)d_in[1];   // [128,36,2]
  const int*   nbr    = (const int*)  d_in[2];   // [4608,16]
  const float* gw     = (const float*)d_in[3];   // [73728,1]
  const float* mrho   = (const float*)d_in[4];
  const float* mth    = (const float*)d_in[5];
  const float* prho   = (const float*)d_in[6];
  const float* pth    = (const float*)d_in[7];
  const float* cw     = (const float*)d_in[8];   // [8,128,1024] == [1024,1024]
  float* out = (float*)d_out;

  // workspace layout (total 20 MB)
  char* ws = (char*)d_ws;
  unsigned short* fb   = (unsigned short*)(ws);              //  9,437,184 B
  unsigned short* wb   = (unsigned short*)(ws + 9437184);    //  2,097,152 B
  unsigned short* proj = (unsigned short*)(ws + 11534336);   //  9,437,184 B

  cast_kernel<<<dim3(((BN_NODES * C_DIM) / 4 + (C_DIM * OUTD) / 4) / 256),
                dim3(256), 0, stream>>>(feats, cw, fb, wb);
  gemm_bt<<<dim3(BN_NODES / TM, OUTD / TN), dim3(256), 0, stream>>>(fb, wb, proj);
  agg_fused<<<dim3(BN_NODES / 2), dim3(256), 0, stream>>>(
      proj, centre, nbr, gw, mrho, mth, prho, pth, out);
}